// Round 3
// baseline (243.336 us; speedup 1.0000x reference)
//
#include <hip/hip_runtime.h>
#include <hip/hip_bf16.h>

#define LSEQ 4096
#define CLEN 8
#define NCHUNK 512

typedef __attribute__((ext_vector_type(8))) short bf16x8;
typedef __attribute__((ext_vector_type(4))) float f32x4;

__device__ __forceinline__ void gl_lds16(const void* g, void* l) {
  __builtin_amdgcn_global_load_lds(
      (const __attribute__((address_space(1))) unsigned int*)g,
      (__attribute__((address_space(3))) unsigned int*)l, 16, 0, 0);
}

__device__ __forceinline__ float silu_f(float v) { return v / (1.0f + __expf(-v)); }

// atan(t) for |t| <= ~0.45 (guaranteed: wr = 1 + e*cos(A0i) > 1, |wi/wr| <= tan(0.38))
__device__ __forceinline__ float atan_small(float t) {
  float t2 = t * t;
  float p = fmaf(t2, fmaf(t2, fmaf(t2, fmaf(t2, 0.11111111f, -0.14285714f), 0.2f),
                          -0.33333333f), 1.0f);
  return t * p;
}

// one scan element: given per-channel consts + La + Ba + Btilde -> (A, Bu)
__device__ __forceinline__ void scan_elem(float A0r, float cz, float sz, float Bcr, float Bci,
                                          float La, float Ba, float btr, float bti,
                                          float& Ar, float& Ai, float& Bur, float& Bui) {
  float e = __expf(A0r + La);
  float wr = fmaf(e, cz, 1.0f), wi = e * sz;
  Ar = 0.5f * __logf(fmaf(wr, wr, wi * wi));
  Ai = atan_small(wi * __builtin_amdgcn_rcpf(wr));
  float pr = Bcr * btr - Bci * bti;
  float pi = Bcr * bti + Bci * btr;
  Bur = pr * Ba;
  Bui = pi * Ba;
}

// ---------------- per-channel constants ----------------
// consts: [0]=A0r [1024]=A0i [2048]=cos(A0i) [3072]=sin(A0i) [4096]=Bcr [5120]=Bci
__global__ void k_const(const float* __restrict__ Lre, const float* __restrict__ Lim,
                        const float* __restrict__ lst, float* __restrict__ consts) {
  int c = threadIdx.x;  // 1024
  int h = c >> 5;
  float s = __expf(lst[h]);
  float lr = Lre[c], li = Lim[c];
  float er = __expf(lr * s);
  float A0r = er * cosf(li * s);
  float A0i = er * sinf(li * s);
  float den = lr * lr + li * li;
  float nr = A0r - 1.0f, ni = A0i;
  consts[c] = A0r;
  consts[1024 + c] = A0i;
  consts[2048 + c] = cosf(A0i);
  consts[3072 + c] = sinf(A0i);
  consts[4096 + c] = (nr * lr + ni * li) / den;
  consts[5120 + c] = (ni * lr - nr * li) / den;
}

// ---------------- x projections ----------------
__global__ __launch_bounds__(256) void k_proj(
    const float* __restrict__ x, const float* __restrict__ Wb, const float* __restrict__ bb,
    const float* __restrict__ Wl, const float* __restrict__ bl,
    const float* __restrict__ Wg, const float* __restrict__ bg,
    const float* __restrict__ Wd, const float* __restrict__ bd,
    __hip_bfloat16* __restrict__ Bp, __hip_bfloat16* __restrict__ Lam,
    float* __restrict__ gt, float* __restrict__ Dp) {
  __shared__ float xs[8][32];
  int tid = threadIdx.x;
  int l0 = blockIdx.x * 8;
  xs[tid >> 5][tid & 31] = x[l0 * 32 + tid];
  __syncthreads();

  float accB[4][8], accL[4][8];
#pragma unroll
  for (int cc = 0; cc < 4; cc++)
#pragma unroll
    for (int ll = 0; ll < 8; ll++) { accB[cc][ll] = 0.f; accL[cc][ll] = 0.f; }

#pragma unroll 8
  for (int h = 0; h < 32; h++) {
    float wb[4], wl[4];
#pragma unroll
    for (int cc = 0; cc < 4; cc++) {
      wb[cc] = Wb[h * 1024 + cc * 256 + tid];
      wl[cc] = Wl[h * 1024 + cc * 256 + tid];
    }
#pragma unroll
    for (int ll = 0; ll < 8; ll++) {
      float xv = xs[ll][h];
#pragma unroll
      for (int cc = 0; cc < 4; cc++) {
        accB[cc][ll] = fmaf(wb[cc], xv, accB[cc][ll]);
        accL[cc][ll] = fmaf(wl[cc], xv, accL[cc][ll]);
      }
    }
  }
#pragma unroll
  for (int cc = 0; cc < 4; cc++) {
    int c = cc * 256 + tid;
    float bbv = bb[c], blv = bl[c];
#pragma unroll
    for (int ll = 0; ll < 8; ll++) {
      int l = l0 + ll;
      Bp[(size_t)(l + 1) * 1024 + c] = __float2bfloat16(accB[cc][ll] + bbv);
      Lam[(size_t)l * 1024 + c] = __float2bfloat16(silu_f(accL[cc][ll] + blv));
    }
  }
  {
    int ll = tid >> 5, jh = tid & 31;
    float a = 0.f;
#pragma unroll
    for (int h = 0; h < 32; h++) a = fmaf(xs[ll][h], Wg[h * 32 + jh], a);
    a += bg[jh];
    gt[(l0 + ll) * 32 + jh] = silu_f(a);
  }
  if (tid < 8) {
    float a = 0.f;
#pragma unroll
    for (int h = 0; h < 32; h++) a = fmaf(xs[tid][h], Wd[h], a);
    a += bd[0];
    Dp[l0 + tid] = (a > 20.f) ? a : log1pf(__expf(a));
  }
}

// ---------------- transpose conv_w (4096x1024 f32) -> WT bf16 (1024x4096) ----------------
__global__ __launch_bounds__(256) void k_transpose(const float* __restrict__ w,
                                                   __hip_bfloat16* __restrict__ WT) {
  __shared__ float t[32][33];
  int k0 = blockIdx.x * 32;
  int n0 = blockIdx.y * 32;
  int r = threadIdx.x >> 5, cidx = threadIdx.x & 31;
#pragma unroll
  for (int i = 0; i < 4; i++)
    t[r + i * 8][cidx] = w[(size_t)(k0 + r + i * 8) * 1024 + n0 + cidx];
  __syncthreads();
#pragma unroll
  for (int i = 0; i < 4; i++) {
    int a = r + i * 8;
    WT[(size_t)(n0 + a) * 4096 + k0 + cidx] = __float2bfloat16(t[cidx][a]);
  }
}

// ---------------- conv-as-GEMM, 2-phase prefetch, epilogue silu -> B_act bf16 ----------------
#define BM 128
#define BN 64
__global__ __launch_bounds__(256) void k_conv_gemm(const __hip_bfloat16* __restrict__ A,
                                                   const __hip_bfloat16* __restrict__ BT,
                                                   const float* __restrict__ cb,
                                                   __hip_bfloat16* __restrict__ Bact) {
  __shared__ __align__(16) __hip_bfloat16 As[2][BM * 64];
  __shared__ __align__(16) __hip_bfloat16 Bs[2][BN * 64];
  int tid = threadIdx.x;
  // XCD-aware swizzle (512 blocks, 512%8==0 -> simple form bijective):
  int bid = blockIdx.x;
  int swz = (bid & 7) * 64 + (bid >> 3);
  int row0 = (swz >> 4) * BM;   // 32 row panels
  int col0 = (swz & 15) * BN;   // 16 col panels
  int lane = tid & 63, wid = tid >> 6;
  int wr = wid >> 1, wc = wid & 1;
  int rA = lane & 15, kg = lane >> 4;
  unsigned wbase = tid & ~63u;

  f32x4 acc[4][2];
#pragma unroll
  for (int m = 0; m < 4; m++)
#pragma unroll
    for (int n = 0; n < 2; n++) acc[m][n] = (f32x4){0.f, 0.f, 0.f, 0.f};

  auto stage = [&](int buf, int ks) {
    int k0 = ks * 64;
#pragma unroll
    for (int i = 0; i < 4; i++) {
      int chunk = i * 256 + tid;
      int m = chunk >> 3, ko = (chunk & 7) * 8;
      gl_lds16(A + (size_t)(row0 + m) * 1024 + k0 + ko, (void*)(As[buf] + (size_t)(i * 256 + wbase) * 8));
    }
#pragma unroll
    for (int i = 0; i < 2; i++) {
      int chunk = i * 256 + tid;
      int n = chunk >> 3, ko = (chunk & 7) * 8;
      gl_lds16(BT + (size_t)(col0 + n) * 4096 + k0 + ko, (void*)(Bs[buf] + (size_t)(i * 256 + wbase) * 8));
    }
  };

  stage(0, 0);
  for (int ks = 0; ks < 64; ks++) {
    __syncthreads();  // s_waitcnt vmcnt(0) lgkmcnt(0) + s_barrier: buf[ks&1] ready, prior reads drained
    if (ks + 1 < 64) stage((ks + 1) & 1, ks + 1);
    const __hip_bfloat16* Ab = As[ks & 1];
    const __hip_bfloat16* Bb = Bs[ks & 1];
    bf16x8 af[4][2], bfg[2][2];
#pragma unroll
    for (int m = 0; m < 4; m++)
#pragma unroll
      for (int kk = 0; kk < 2; kk++)
        af[m][kk] = *(const bf16x8*)(Ab + (wr * 64 + m * 16 + rA) * 64 + kk * 32 + kg * 8);
#pragma unroll
    for (int n = 0; n < 2; n++)
#pragma unroll
      for (int kk = 0; kk < 2; kk++)
        bfg[n][kk] = *(const bf16x8*)(Bb + (wc * 32 + n * 16 + rA) * 64 + kk * 32 + kg * 8);
#pragma unroll
    for (int m = 0; m < 4; m++)
#pragma unroll
      for (int n = 0; n < 2; n++)
#pragma unroll
        for (int kk = 0; kk < 2; kk++)
          acc[m][n] = __builtin_amdgcn_mfma_f32_16x16x32_bf16(af[m][kk], bfg[n][kk], acc[m][n], 0, 0, 0);
  }
#pragma unroll
  for (int m = 0; m < 4; m++)
#pragma unroll
    for (int n = 0; n < 2; n++) {
      int col = col0 + wc * 32 + n * 16 + (lane & 15);
      float cbv = cb[col];
#pragma unroll
      for (int r = 0; r < 4; r++) {
        int row = row0 + wr * 64 + m * 16 + (lane >> 4) * 4 + r;
        Bact[(size_t)row * 1024 + col] = __float2bfloat16(silu_f(acc[m][n][r] + cbv));
      }
    }
}

// ---------------- scan pass A: per (chunk, channel) aggregate only ----------------
__global__ __launch_bounds__(256) void k_scanA(const float* __restrict__ consts,
                                               const __hip_bfloat16* __restrict__ Lam,
                                               const __hip_bfloat16* __restrict__ Bact,
                                               const float* __restrict__ Bin,
                                               float4* __restrict__ Agg) {
  int tid = threadIdx.x;
  int chunk = blockIdx.x >> 2;           // 512 chunks
  int c = (blockIdx.x & 3) * 256 + tid;  // 1024 channels
  int j = c & 31;
  float A0r = consts[c], cz = consts[2048 + c], sz = consts[3072 + c];
  float Bcr = consts[4096 + c], Bci = consts[5120 + c];
  float ar = 1.f, ai = 0.f, br = 0.f, bi = 0.f;
  int l = chunk * CLEN;
#pragma unroll
  for (int it = 0; it < CLEN; it++, l++) {
    float La = __bfloat162float(Lam[(size_t)l * 1024 + c]);
    float Ba = __bfloat162float(Bact[(size_t)l * 1024 + c]);
    float2 bt = *(const float2*)(Bin + (size_t)l * 64 + j * 2);
    float Ar, Ai, Bur, Bui;
    scan_elem(A0r, cz, sz, Bcr, Bci, La, Ba, bt.x, bt.y, Ar, Ai, Bur, Bui);
    float nbr = Ar * br - Ai * bi + Bur;
    float nbi = Ar * bi + Ai * br + Bui;
    br = nbr; bi = nbi;
    float nar = Ar * ar - Ai * ai;
    float nai = Ar * ai + Ai * ar;
    ar = nar; ai = nai;
  }
  Agg[(size_t)chunk * 1024 + c] = make_float4(ar, ai, br, bi);
}

// ---------------- scan pass B: exclusive carries per (chunk, channel) ----------------
__global__ __launch_bounds__(256) void k_scanB(const float4* __restrict__ Agg,
                                               float2* __restrict__ Carry) {
  int tid = threadIdx.x;
  int lane = tid & 63;
  int ch = blockIdx.x * 4 + (tid >> 6);  // 256 blocks x 4 channels
  float pr[8], pi_[8], qr[8], qi[8];
  float mAr = 1.f, mAi = 0.f, mBr = 0.f, mBi = 0.f;
#pragma unroll
  for (int u = 0; u < 8; u++) {
    pr[u] = mAr; pi_[u] = mAi; qr[u] = mBr; qi[u] = mBi;
    float4 g = Agg[(size_t)(lane * 8 + u) * 1024 + ch];
    float nAr = g.x * mAr - g.y * mAi;
    float nAi = g.x * mAi + g.y * mAr;
    float nBr = g.x * mBr - g.y * mBi + g.z;
    float nBi = g.x * mBi + g.y * mBr + g.w;
    mAr = nAr; mAi = nAi; mBr = nBr; mBi = nBi;
  }
  float SAr = mAr, SAi = mAi, SBr = mBr, SBi = mBi;
#pragma unroll
  for (int d = 1; d < 64; d <<= 1) {
    float tAr = __shfl_up(SAr, (unsigned)d, 64);
    float tAi = __shfl_up(SAi, (unsigned)d, 64);
    float tBr = __shfl_up(SBr, (unsigned)d, 64);
    float tBi = __shfl_up(SBi, (unsigned)d, 64);
    if (lane >= d) {
      float nAr = SAr * tAr - SAi * tAi;
      float nAi = SAr * tAi + SAi * tAr;
      float nBr = SAr * tBr - SAi * tBi + SBr;
      float nBi = SAr * tBi + SAi * tBr + SBi;
      SAr = nAr; SAi = nAi; SBr = nBr; SBi = nBi;
    }
  }
  float EBr = __shfl_up(SBr, 1u, 64);
  float EBi = __shfl_up(SBi, 1u, 64);
  if (lane == 0) { EBr = 0.f; EBi = 0.f; }
#pragma unroll
  for (int u = 0; u < 8; u++) {
    float sr = pr[u] * EBr - pi_[u] * EBi + qr[u];
    float si = pr[u] * EBi + pi_[u] * EBr + qi[u];
    Carry[(size_t)(lane * 8 + u) * 1024 + ch] = make_float2(sr, si);
  }
}

// ---------------- scan pass C: recompute local scan + ys + gate + out GEMM ----------------
__global__ __launch_bounds__(256) void k_scanC(const float* __restrict__ consts,
                                               const __hip_bfloat16* __restrict__ Lam,
                                               const __hip_bfloat16* __restrict__ Bact,
                                               const float* __restrict__ Bin,
                                               const float* __restrict__ Cin,
                                               const float2* __restrict__ Carry,
                                               const float* __restrict__ x,
                                               const float* __restrict__ gt,
                                               const float* __restrict__ Dp,
                                               const float* __restrict__ Wo,
                                               const float* __restrict__ bo,
                                               float* __restrict__ out) {
  __shared__ float part[4][CLEN][32];
  __shared__ float Wo_s[1024];
  __shared__ float ht_s[CLEN][32];
  int tid = threadIdx.x;
  int chunk = blockIdx.x;  // 512
  int l0 = chunk * CLEN;
  int wave = tid >> 6, lane = tid & 63;
#pragma unroll
  for (int i = 0; i < 4; i++) Wo_s[i * 256 + tid] = Wo[i * 256 + tid];

  float yp[CLEN];
#pragma unroll
  for (int it = 0; it < CLEN; it++) yp[it] = 0.f;

#pragma unroll
  for (int g = 0; g < 4; g++) {
    int c = g * 256 + tid;
    int j = c & 31, p = c >> 5;
    float A0r = consts[c], cz = consts[2048 + c], sz = consts[3072 + c];
    float Bcr = consts[4096 + c], Bci = consts[5120 + c];
    float2 s = Carry[(size_t)chunk * 1024 + c];
    float xr = s.x, xi = s.y;
#pragma unroll
    for (int it = 0; it < CLEN; it++) {
      int l = l0 + it;
      float La = __bfloat162float(Lam[(size_t)l * 1024 + c]);
      float Ba = __bfloat162float(Bact[(size_t)l * 1024 + c]);
      float2 bt = *(const float2*)(Bin + (size_t)l * 64 + j * 2);
      float Ar, Ai, Bur, Bui;
      scan_elem(A0r, cz, sz, Bcr, Bci, La, Ba, bt.x, bt.y, Ar, Ai, Bur, Bui);
      float nxr = Ar * xr - Ai * xi + Bur;
      float nxi = Ar * xi + Ai * xr + Bui;
      xr = nxr; xi = nxi;
      float2 cv = *(const float2*)(Cin + (size_t)l * 64 + p * 2);
      yp[it] = fmaf(cv.x, xr, yp[it]);
      yp[it] = fmaf(-cv.y, xi, yp[it]);
    }
  }
  // reduce over p: fold lane+32 into lane, then 4 wave-partials via LDS
#pragma unroll
  for (int it = 0; it < CLEN; it++) yp[it] += __shfl_down(yp[it], 32u, 64);
  if (lane < 32) {
#pragma unroll
    for (int it = 0; it < CLEN; it++) part[wave][it][lane] = yp[it];
  }
  __syncthreads();
  int ll = tid >> 5, j = tid & 31;
  float ys = part[0][ll][j] + part[1][ll][j] + part[2][ll][j] + part[3][ll][j];
  int l = l0 + ll;
  float xv = x[l * 32 + j];
  float g = gt[l * 32 + j];
  float d = Dp[l];
  float ht = (1.0f - g) * (ys + d * xv) + g * xv;
  ht_s[ll][j] = ht;
  __syncthreads();
  float accv = bo[j];
#pragma unroll
  for (int jj = 0; jj < 32; jj++) accv = fmaf(ht_s[ll][jj], Wo_s[jj * 32 + j], accv);
  out[l * 32 + j] = accv;
}

extern "C" void kernel_launch(void* const* d_in, const int* in_sizes, int n_in,
                              void* d_out, int out_size, void* d_ws, size_t ws_size,
                              hipStream_t stream) {
  const float* x   = (const float*)d_in[0];
  const float* Lre = (const float*)d_in[1];
  const float* Lim = (const float*)d_in[2];
  const float* Bin = (const float*)d_in[3];
  const float* Cin = (const float*)d_in[4];
  const float* lst = (const float*)d_in[5];
  const float* Wb  = (const float*)d_in[6];
  const float* bb  = (const float*)d_in[7];
  const float* Wl  = (const float*)d_in[8];
  const float* bl  = (const float*)d_in[9];
  const float* cw  = (const float*)d_in[10];
  const float* cb  = (const float*)d_in[11];
  const float* Wg  = (const float*)d_in[12];
  const float* bg  = (const float*)d_in[13];
  const float* Wd  = (const float*)d_in[14];
  const float* bd  = (const float*)d_in[15];
  const float* Wo  = (const float*)d_in[16];
  const float* bo  = (const float*)d_in[17];
  float* out = (float*)d_out;

  char* ws = (char*)d_ws;
  size_t off = 0;
  auto alloc = [&](size_t bytes) {
    char* p = ws + off;
    off = (off + bytes + 255) & ~(size_t)255;
    return p;
  };
  float* consts          = (float*)alloc(6 * 1024 * 4);
  __hip_bfloat16* Bp     = (__hip_bfloat16*)alloc((size_t)(LSEQ + 3) * 1024 * 2);
  __hip_bfloat16* WT     = (__hip_bfloat16*)alloc((size_t)1024 * 4096 * 2);
  __hip_bfloat16* Lam    = (__hip_bfloat16*)alloc((size_t)LSEQ * 1024 * 2);
  __hip_bfloat16* Bact   = (__hip_bfloat16*)alloc((size_t)LSEQ * 1024 * 2);
  float* gt              = (float*)alloc((size_t)LSEQ * 32 * 4);
  float* Dp              = (float*)alloc((size_t)LSEQ * 4);
  float4* Agg            = (float4*)alloc((size_t)NCHUNK * 1024 * 16);
  float2* Carry          = (float2*)alloc((size_t)NCHUNK * 1024 * 8);

  hipMemsetAsync(Bp, 0, 1024 * 2, stream);
  hipMemsetAsync(Bp + (size_t)(LSEQ + 1) * 1024, 0, 2 * 1024 * 2, stream);

  k_const<<<1, 1024, 0, stream>>>(Lre, Lim, lst, consts);
  k_proj<<<LSEQ / 8, 256, 0, stream>>>(x, Wb, bb, Wl, bl, Wg, bg, Wd, bd, Bp, Lam, gt, Dp);
  k_transpose<<<dim3(128, 32), 256, 0, stream>>>(cw, WT);
  k_conv_gemm<<<512, 256, 0, stream>>>(Bp, WT, cb, Bact);
  k_scanA<<<4 * NCHUNK, 256, 0, stream>>>(consts, Lam, Bact, Bin, Agg);
  k_scanB<<<256, 256, 0, stream>>>(Agg, Carry);
  k_scanC<<<NCHUNK, 256, 0, stream>>>(consts, Lam, Bact, Bin, Cin, Carry, x, gt, Dp, Wo, bo, out);
}

// Round 4
// 215.692 us; speedup vs baseline: 1.1282x; 1.1282x over previous
//
#include <hip/hip_runtime.h>
#include <hip/hip_bf16.h>

#define LSEQ 4096
#define CLEN 8
#define NCHUNK 512

typedef __attribute__((ext_vector_type(8))) short bf16x8;
typedef __attribute__((ext_vector_type(4))) float f32x4;

__device__ __forceinline__ void gl_lds16(const void* g, void* l) {
  __builtin_amdgcn_global_load_lds(
      (const __attribute__((address_space(1))) unsigned int*)g,
      (__attribute__((address_space(3))) unsigned int*)l, 16, 0, 0);
}

__device__ __forceinline__ float silu_f(float v) { return v / (1.0f + __expf(-v)); }

// atan(t) for |t| <= ~0.45 (guaranteed: wr = 1 + e*cos(A0i) > 1, |wi/wr| small)
__device__ __forceinline__ float atan_small(float t) {
  float t2 = t * t;
  float p = fmaf(t2, fmaf(t2, fmaf(t2, fmaf(t2, 0.11111111f, -0.14285714f), 0.2f),
                          -0.33333333f), 1.0f);
  return t * p;
}

__device__ __forceinline__ void scan_elem(float A0r, float cz, float sz, float Bcr, float Bci,
                                          float La, float Ba, float btr, float bti,
                                          float& Ar, float& Ai, float& Bur, float& Bui) {
  float e = __expf(A0r + La);
  float wr = fmaf(e, cz, 1.0f), wi = e * sz;
  Ar = 0.5f * __logf(fmaf(wr, wr, wi * wi));
  Ai = atan_small(wi * __builtin_amdgcn_rcpf(wr));
  float pr = Bcr * btr - Bci * bti;
  float pi = Bcr * bti + Bci * btr;
  Bur = pr * Ba;
  Bui = pi * Ba;
}

// ================= fused prep kernel =================
// blocks [0, 4096)            : transpose conv_w tiles -> WT bf16 (1024 x 4096)
// blocks [4096, 4608)         : proj (8 l-rows each); block 4096 also zeroes Bp pad rows
// block  4608                 : per-channel consts
__global__ __launch_bounds__(256) void k_prep(
    const float* __restrict__ x, const float* __restrict__ Wb, const float* __restrict__ bb,
    const float* __restrict__ Wl, const float* __restrict__ bl,
    const float* __restrict__ Wg, const float* __restrict__ bg,
    const float* __restrict__ Wd, const float* __restrict__ bd,
    const float* __restrict__ cw,
    const float* __restrict__ Lre, const float* __restrict__ Lim, const float* __restrict__ lst,
    __hip_bfloat16* __restrict__ Bp, __hip_bfloat16* __restrict__ Lam,
    float* __restrict__ gt, float* __restrict__ Dp,
    __hip_bfloat16* __restrict__ WT, float* __restrict__ consts) {
  int b = blockIdx.x;
  int tid = threadIdx.x;
  if (b < 4096) {
    // ---- transpose: 32x32 tile of conv_w (4096 x 1024) -> WT (1024 x 4096) bf16
    __shared__ float t[32][33];
    int k0 = (b & 127) * 32;
    int n0 = (b >> 7) * 32;
    int r = tid >> 5, cidx = tid & 31;
#pragma unroll
    for (int i = 0; i < 4; i++)
      t[r + i * 8][cidx] = cw[(size_t)(k0 + r + i * 8) * 1024 + n0 + cidx];
    __syncthreads();
#pragma unroll
    for (int i = 0; i < 4; i++) {
      int a = r + i * 8;
      WT[(size_t)(n0 + a) * 4096 + k0 + cidx] = __float2bfloat16(t[cidx][a]);
    }
    return;
  }
  if (b < 4608) {
    int pb = b - 4096;
    if (pb == 0) {
      // zero Bp pad rows: row 0, rows LSEQ+1, LSEQ+2
#pragma unroll
      for (int i = 0; i < 4; i++) {
        int c = i * 256 + tid;
        Bp[c] = __float2bfloat16(0.f);
        Bp[(size_t)(LSEQ + 1) * 1024 + c] = __float2bfloat16(0.f);
        Bp[(size_t)(LSEQ + 2) * 1024 + c] = __float2bfloat16(0.f);
      }
    }
    __shared__ float xs[8][32];
    int l0 = pb * 8;
    xs[tid >> 5][tid & 31] = x[l0 * 32 + tid];
    __syncthreads();

    float accB[4][8], accL[4][8];
#pragma unroll
    for (int cc = 0; cc < 4; cc++)
#pragma unroll
      for (int ll = 0; ll < 8; ll++) { accB[cc][ll] = 0.f; accL[cc][ll] = 0.f; }

#pragma unroll 8
    for (int h = 0; h < 32; h++) {
      float wb[4], wl[4];
#pragma unroll
      for (int cc = 0; cc < 4; cc++) {
        wb[cc] = Wb[h * 1024 + cc * 256 + tid];
        wl[cc] = Wl[h * 1024 + cc * 256 + tid];
      }
#pragma unroll
      for (int ll = 0; ll < 8; ll++) {
        float xv = xs[ll][h];
#pragma unroll
        for (int cc = 0; cc < 4; cc++) {
          accB[cc][ll] = fmaf(wb[cc], xv, accB[cc][ll]);
          accL[cc][ll] = fmaf(wl[cc], xv, accL[cc][ll]);
        }
      }
    }
#pragma unroll
    for (int cc = 0; cc < 4; cc++) {
      int c = cc * 256 + tid;
      float bbv = bb[c], blv = bl[c];
#pragma unroll
      for (int ll = 0; ll < 8; ll++) {
        int l = l0 + ll;
        Bp[(size_t)(l + 1) * 1024 + c] = __float2bfloat16(accB[cc][ll] + bbv);
        Lam[(size_t)l * 1024 + c] = __float2bfloat16(silu_f(accL[cc][ll] + blv));
      }
    }
    {
      int ll = tid >> 5, jh = tid & 31;
      float a = 0.f;
#pragma unroll
      for (int h = 0; h < 32; h++) a = fmaf(xs[ll][h], Wg[h * 32 + jh], a);
      a += bg[jh];
      gt[(l0 + ll) * 32 + jh] = silu_f(a);
    }
    if (tid < 8) {
      float a = 0.f;
#pragma unroll
      for (int h = 0; h < 32; h++) a = fmaf(xs[tid][h], Wd[h], a);
      a += bd[0];
      Dp[l0 + tid] = (a > 20.f) ? a : log1pf(__expf(a));
    }
    return;
  }
  // ---- consts: 1024 channels, 4 per thread
#pragma unroll
  for (int i = 0; i < 4; i++) {
    int c = i * 256 + tid;
    int h = c >> 5;
    float s = __expf(lst[h]);
    float lr = Lre[c], li = Lim[c];
    float er = __expf(lr * s);
    float A0r = er * cosf(li * s);
    float A0i = er * sinf(li * s);
    float den = lr * lr + li * li;
    float nr = A0r - 1.0f, ni = A0i;
    consts[c] = A0r;
    consts[1024 + c] = A0i;
    consts[2048 + c] = cosf(A0i);
    consts[3072 + c] = sinf(A0i);
    consts[4096 + c] = (nr * lr + ni * li) / den;
    consts[5120 + c] = (ni * lr - nr * li) / den;
  }
}

// ================= conv-as-GEMM (round-2 structure + XCD swizzle) =================
#define BM 128
#define BN 64
__global__ __launch_bounds__(256) void k_conv_gemm(const __hip_bfloat16* __restrict__ A,
                                                   const __hip_bfloat16* __restrict__ BT,
                                                   const float* __restrict__ cb,
                                                   __hip_bfloat16* __restrict__ Bact) {
  __shared__ __align__(16) __hip_bfloat16 As[BM * 64];
  __shared__ __align__(16) __hip_bfloat16 Bs[BN * 64];
  int tid = threadIdx.x;
  // XCD swizzle (512 blocks, 512%8==0 -> simple form bijective)
  int bid = blockIdx.x;
  int swz = (bid & 7) * 64 + (bid >> 3);
  int row0 = (swz >> 4) * BM;
  int col0 = (swz & 15) * BN;
  int lane = tid & 63, wid = tid >> 6;
  int wr = wid >> 1, wc = wid & 1;
  int rA = lane & 15, kg = lane >> 4;
  unsigned wbase = tid & ~63u;

  f32x4 acc[4][2];
#pragma unroll
  for (int m = 0; m < 4; m++)
#pragma unroll
    for (int n = 0; n < 2; n++) acc[m][n] = (f32x4){0.f, 0.f, 0.f, 0.f};

  for (int ks = 0; ks < 64; ks++) {
    int k0 = ks * 64;
#pragma unroll
    for (int i = 0; i < 4; i++) {
      int chunk = i * 256 + tid;
      int m = chunk >> 3, ko = (chunk & 7) * 8;
      gl_lds16(A + (size_t)(row0 + m) * 1024 + k0 + ko, (void*)(As + (size_t)(i * 256 + wbase) * 8));
    }
#pragma unroll
    for (int i = 0; i < 2; i++) {
      int chunk = i * 256 + tid;
      int n = chunk >> 3, ko = (chunk & 7) * 8;
      gl_lds16(BT + (size_t)(col0 + n) * 4096 + k0 + ko, (void*)(Bs + (size_t)(i * 256 + wbase) * 8));
    }
    __syncthreads();

    bf16x8 af[4][2], bfg[2][2];
#pragma unroll
    for (int m = 0; m < 4; m++)
#pragma unroll
      for (int kk = 0; kk < 2; kk++)
        af[m][kk] = *(const bf16x8*)(As + (wr * 64 + m * 16 + rA) * 64 + kk * 32 + kg * 8);
#pragma unroll
    for (int n = 0; n < 2; n++)
#pragma unroll
      for (int kk = 0; kk < 2; kk++)
        bfg[n][kk] = *(const bf16x8*)(Bs + (wc * 32 + n * 16 + rA) * 64 + kk * 32 + kg * 8);
#pragma unroll
    for (int m = 0; m < 4; m++)
#pragma unroll
      for (int n = 0; n < 2; n++)
#pragma unroll
        for (int kk = 0; kk < 2; kk++)
          acc[m][n] = __builtin_amdgcn_mfma_f32_16x16x32_bf16(af[m][kk], bfg[n][kk], acc[m][n], 0, 0, 0);
    __syncthreads();
  }
#pragma unroll
  for (int m = 0; m < 4; m++)
#pragma unroll
    for (int n = 0; n < 2; n++) {
      int col = col0 + wc * 32 + n * 16 + (lane & 15);
      float cbv = cb[col];
#pragma unroll
      for (int r = 0; r < 4; r++) {
        int row = row0 + wr * 64 + m * 16 + (lane >> 4) * 4 + r;
        Bact[(size_t)row * 1024 + col] = __float2bfloat16(silu_f(acc[m][n][r] + cbv));
      }
    }
}

// ================= scan pass A: per (chunk, channel) aggregates =================
__global__ __launch_bounds__(256) void k_scanA(const float* __restrict__ consts,
                                               const __hip_bfloat16* __restrict__ Lam,
                                               const __hip_bfloat16* __restrict__ Bact,
                                               const float* __restrict__ Bin,
                                               float4* __restrict__ Agg) {
  int tid = threadIdx.x;
  int chunk = blockIdx.x >> 2;
  int c = (blockIdx.x & 3) * 256 + tid;
  int j = c & 31;
  float A0r = consts[c], cz = consts[2048 + c], sz = consts[3072 + c];
  float Bcr = consts[4096 + c], Bci = consts[5120 + c];
  float ar = 1.f, ai = 0.f, br = 0.f, bi = 0.f;
  int l = chunk * CLEN;
#pragma unroll
  for (int it = 0; it < CLEN; it++, l++) {
    float La = __bfloat162float(Lam[(size_t)l * 1024 + c]);
    float Ba = __bfloat162float(Bact[(size_t)l * 1024 + c]);
    float2 bt = *(const float2*)(Bin + (size_t)l * 64 + j * 2);
    float Ar, Ai, Bur, Bui;
    scan_elem(A0r, cz, sz, Bcr, Bci, La, Ba, bt.x, bt.y, Ar, Ai, Bur, Bui);
    float nbr = Ar * br - Ai * bi + Bur;
    float nbi = Ar * bi + Ai * br + Bui;
    br = nbr; bi = nbi;
    float nar = Ar * ar - Ai * ai;
    float nai = Ar * ai + Ai * ar;
    ar = nar; ai = nai;
  }
  Agg[(size_t)chunk * 1024 + c] = make_float4(ar, ai, br, bi);
}

// ================= scan pass B: exclusive carries =================
__global__ __launch_bounds__(256) void k_scanB(const float4* __restrict__ Agg,
                                               float2* __restrict__ Carry) {
  int tid = threadIdx.x;
  int lane = tid & 63;
  int ch = blockIdx.x * 4 + (tid >> 6);
  float pr[8], pi_[8], qr[8], qi[8];
  float mAr = 1.f, mAi = 0.f, mBr = 0.f, mBi = 0.f;
#pragma unroll
  for (int u = 0; u < 8; u++) {
    pr[u] = mAr; pi_[u] = mAi; qr[u] = mBr; qi[u] = mBi;
    float4 g = Agg[(size_t)(lane * 8 + u) * 1024 + ch];
    float nAr = g.x * mAr - g.y * mAi;
    float nAi = g.x * mAi + g.y * mAr;
    float nBr = g.x * mBr - g.y * mBi + g.z;
    float nBi = g.x * mBi + g.y * mBr + g.w;
    mAr = nAr; mAi = nAi; mBr = nBr; mBi = nBi;
  }
  float SAr = mAr, SAi = mAi, SBr = mBr, SBi = mBi;
#pragma unroll
  for (int d = 1; d < 64; d <<= 1) {
    float tAr = __shfl_up(SAr, (unsigned)d, 64);
    float tAi = __shfl_up(SAi, (unsigned)d, 64);
    float tBr = __shfl_up(SBr, (unsigned)d, 64);
    float tBi = __shfl_up(SBi, (unsigned)d, 64);
    if (lane >= d) {
      float nAr = SAr * tAr - SAi * tAi;
      float nAi = SAr * tAi + SAi * tAr;
      float nBr = SAr * tBr - SAi * tBi + SBr;
      float nBi = SAr * tBi + SAi * tBr + SBi;
      SAr = nAr; SAi = nAi; SBr = nBr; SBi = nBi;
    }
  }
  float EBr = __shfl_up(SBr, 1u, 64);
  float EBi = __shfl_up(SBi, 1u, 64);
  if (lane == 0) { EBr = 0.f; EBi = 0.f; }
#pragma unroll
  for (int u = 0; u < 8; u++) {
    float sr = pr[u] * EBr - pi_[u] * EBi + qr[u];
    float si = pr[u] * EBi + pi_[u] * EBr + qi[u];
    Carry[(size_t)(lane * 8 + u) * 1024 + ch] = make_float2(sr, si);
  }
}

// ================= scan pass C: recompute + ys + gate + out GEMM =================
__global__ __launch_bounds__(256) void k_scanC(const float* __restrict__ consts,
                                               const __hip_bfloat16* __restrict__ Lam,
                                               const __hip_bfloat16* __restrict__ Bact,
                                               const float* __restrict__ Bin,
                                               const float* __restrict__ Cin,
                                               const float2* __restrict__ Carry,
                                               const float* __restrict__ x,
                                               const float* __restrict__ gt,
                                               const float* __restrict__ Dp,
                                               const float* __restrict__ Wo,
                                               const float* __restrict__ bo,
                                               float* __restrict__ out) {
  __shared__ float part[4][CLEN][32];
  __shared__ float Wo_s[1024];
  __shared__ float ht_s[CLEN][32];
  int tid = threadIdx.x;
  int chunk = blockIdx.x;
  int l0 = chunk * CLEN;
  int wave = tid >> 6, lane = tid & 63;
#pragma unroll
  for (int i = 0; i < 4; i++) Wo_s[i * 256 + tid] = Wo[i * 256 + tid];

  float yp[CLEN];
#pragma unroll
  for (int it = 0; it < CLEN; it++) yp[it] = 0.f;

#pragma unroll
  for (int g = 0; g < 4; g++) {
    int c = g * 256 + tid;
    int j = c & 31, p = c >> 5;
    float A0r = consts[c], cz = consts[2048 + c], sz = consts[3072 + c];
    float Bcr = consts[4096 + c], Bci = consts[5120 + c];
    float2 s = Carry[(size_t)chunk * 1024 + c];
    float xr = s.x, xi = s.y;
#pragma unroll
    for (int it = 0; it < CLEN; it++) {
      int l = l0 + it;
      float La = __bfloat162float(Lam[(size_t)l * 1024 + c]);
      float Ba = __bfloat162float(Bact[(size_t)l * 1024 + c]);
      float2 bt = *(const float2*)(Bin + (size_t)l * 64 + j * 2);
      float Ar, Ai, Bur, Bui;
      scan_elem(A0r, cz, sz, Bcr, Bci, La, Ba, bt.x, bt.y, Ar, Ai, Bur, Bui);
      float nxr = Ar * xr - Ai * xi + Bur;
      float nxi = Ar * xi + Ai * xr + Bui;
      xr = nxr; xi = nxi;
      float2 cv = *(const float2*)(Cin + (size_t)l * 64 + p * 2);
      yp[it] = fmaf(cv.x, xr, yp[it]);
      yp[it] = fmaf(-cv.y, xi, yp[it]);
    }
  }
#pragma unroll
  for (int it = 0; it < CLEN; it++) yp[it] += __shfl_down(yp[it], 32u, 64);
  if (lane < 32) {
#pragma unroll
    for (int it = 0; it < CLEN; it++) part[wave][it][lane] = yp[it];
  }
  __syncthreads();
  int ll = tid >> 5, j = tid & 31;
  float ys = part[0][ll][j] + part[1][ll][j] + part[2][ll][j] + part[3][ll][j];
  int l = l0 + ll;
  float xv = x[l * 32 + j];
  float g = gt[l * 32 + j];
  float d = Dp[l];
  float ht = (1.0f - g) * (ys + d * xv) + g * xv;
  ht_s[ll][j] = ht;
  __syncthreads();
  float accv = bo[j];
#pragma unroll
  for (int jj = 0; jj < 32; jj++) accv = fmaf(ht_s[ll][jj], Wo_s[jj * 32 + j], accv);
  out[l * 32 + j] = accv;
}

extern "C" void kernel_launch(void* const* d_in, const int* in_sizes, int n_in,
                              void* d_out, int out_size, void* d_ws, size_t ws_size,
                              hipStream_t stream) {
  const float* x   = (const float*)d_in[0];
  const float* Lre = (const float*)d_in[1];
  const float* Lim = (const float*)d_in[2];
  const float* Bin = (const float*)d_in[3];
  const float* Cin = (const float*)d_in[4];
  const float* lst = (const float*)d_in[5];
  const float* Wb  = (const float*)d_in[6];
  const float* bb  = (const float*)d_in[7];
  const float* Wl  = (const float*)d_in[8];
  const float* bl  = (const float*)d_in[9];
  const float* cw  = (const float*)d_in[10];
  const float* cb  = (const float*)d_in[11];
  const float* Wg  = (const float*)d_in[12];
  const float* bg  = (const float*)d_in[13];
  const float* Wd  = (const float*)d_in[14];
  const float* bd  = (const float*)d_in[15];
  const float* Wo  = (const float*)d_in[16];
  const float* bo  = (const float*)d_in[17];
  float* out = (float*)d_out;

  char* ws = (char*)d_ws;
  size_t off = 0;
  auto alloc = [&](size_t bytes) {
    char* p = ws + off;
    off = (off + bytes + 255) & ~(size_t)255;
    return p;
  };
  float* consts          = (float*)alloc(6 * 1024 * 4);
  __hip_bfloat16* Bp     = (__hip_bfloat16*)alloc((size_t)(LSEQ + 3) * 1024 * 2);
  __hip_bfloat16* WT     = (__hip_bfloat16*)alloc((size_t)1024 * 4096 * 2);
  __hip_bfloat16* Lam    = (__hip_bfloat16*)alloc((size_t)LSEQ * 1024 * 2);
  __hip_bfloat16* Bact   = (__hip_bfloat16*)alloc((size_t)LSEQ * 1024 * 2);
  float* gt              = (float*)alloc((size_t)LSEQ * 32 * 4);
  float* Dp              = (float*)alloc((size_t)LSEQ * 4);
  float4* Agg            = (float4*)alloc((size_t)NCHUNK * 1024 * 16);
  float2* Carry          = (float2*)alloc((size_t)NCHUNK * 1024 * 8);

  k_prep<<<4609, 256, 0, stream>>>(x, Wb, bb, Wl, bl, Wg, bg, Wd, bd, cw,
                                   Lre, Lim, lst, Bp, Lam, gt, Dp, WT, consts);
  k_conv_gemm<<<512, 256, 0, stream>>>(Bp, WT, cb, Bact);
  k_scanA<<<4 * NCHUNK, 256, 0, stream>>>(consts, Lam, Bact, Bin, Agg);
  k_scanB<<<256, 256, 0, stream>>>(Agg, Carry);
  k_scanC<<<NCHUNK, 256, 0, stream>>>(consts, Lam, Bact, Bin, Cin, Carry, x, gt, Dp, Wo, bo, out);
}

// Round 8
// 196.252 us; speedup vs baseline: 1.2399x; 1.0991x over previous
//
#include <hip/hip_runtime.h>
#include <hip/hip_bf16.h>

#define LSEQ 4096
#define CLEN 8
#define NCHUNK 512

typedef __attribute__((ext_vector_type(8))) short bf16x8;
typedef __attribute__((ext_vector_type(4))) float f32x4;

__device__ __forceinline__ void gl_lds16(const void* g, void* l) {
  __builtin_amdgcn_global_load_lds(
      (const __attribute__((address_space(1))) unsigned int*)g,
      (__attribute__((address_space(3))) unsigned int*)l, 16, 0, 0);
}

__device__ __forceinline__ float silu_f(float v) { return v / (1.0f + __expf(-v)); }

// bf16 pair (packed in u32) -> two floats (bf16 is the high half of f32)
__device__ __forceinline__ float bf_lo(unsigned v) { return __uint_as_float(v << 16); }
__device__ __forceinline__ float bf_hi(unsigned v) { return __uint_as_float(v & 0xffff0000u); }

// atan(t) for |t| <= ~0.8 (wr = 1 + e*cos(A0i) > 1.4 guaranteed)
__device__ __forceinline__ float atan_small(float t) {
  float t2 = t * t;
  float p = fmaf(t2, fmaf(t2, fmaf(t2, fmaf(t2, 0.11111111f, -0.14285714f), 0.2f),
                          -0.33333333f), 1.0f);
  return t * p;
}

__device__ __forceinline__ void scan_elem(float A0r, float cz, float sz, float Bcr, float Bci,
                                          float La, float Ba, float btr, float bti,
                                          float& Ar, float& Ai, float& Bur, float& Bui) {
  float e = __expf(A0r + La);
  float wr = fmaf(e, cz, 1.0f), wi = e * sz;
  Ar = 0.5f * __logf(fmaf(wr, wr, wi * wi));
  Ai = atan_small(wi * __builtin_amdgcn_rcpf(wr));
  float pr = Bcr * btr - Bci * bti;
  float pi = Bcr * bti + Bci * btr;
  Bur = pr * Ba;
  Bui = pi * Ba;
}

// ================= fused prep kernel =================
// blocks [0,4096): transpose conv_w -> WT bf16; [4096,4608): proj; 4608: consts
__global__ __launch_bounds__(256) void k_prep(
    const float* __restrict__ x, const float* __restrict__ Wb, const float* __restrict__ bb,
    const float* __restrict__ Wl, const float* __restrict__ bl,
    const float* __restrict__ Wg, const float* __restrict__ bg,
    const float* __restrict__ Wd, const float* __restrict__ bd,
    const float* __restrict__ cw,
    const float* __restrict__ Lre, const float* __restrict__ Lim, const float* __restrict__ lst,
    __hip_bfloat16* __restrict__ Bp, __hip_bfloat16* __restrict__ Lam,
    float* __restrict__ gt, float* __restrict__ Dp,
    __hip_bfloat16* __restrict__ WT, float* __restrict__ consts) {
  int b = blockIdx.x;
  int tid = threadIdx.x;
  if (b < 4096) {
    __shared__ float t[32][33];
    int k0 = (b & 127) * 32;
    int n0 = (b >> 7) * 32;
    int r = tid >> 5, cidx = tid & 31;
#pragma unroll
    for (int i = 0; i < 4; i++)
      t[r + i * 8][cidx] = cw[(size_t)(k0 + r + i * 8) * 1024 + n0 + cidx];
    __syncthreads();
#pragma unroll
    for (int i = 0; i < 4; i++) {
      int a = r + i * 8;
      WT[(size_t)(n0 + a) * 4096 + k0 + cidx] = __float2bfloat16(t[cidx][a]);
    }
    return;
  }
  if (b < 4608) {
    int pb = b - 4096;
    if (pb == 0) {
#pragma unroll
      for (int i = 0; i < 4; i++) {
        int c = i * 256 + tid;
        Bp[c] = __float2bfloat16(0.f);
        Bp[(size_t)(LSEQ + 1) * 1024 + c] = __float2bfloat16(0.f);
        Bp[(size_t)(LSEQ + 2) * 1024 + c] = __float2bfloat16(0.f);
      }
    }
    __shared__ float xs[8][32];
    int l0 = pb * 8;
    xs[tid >> 5][tid & 31] = x[l0 * 32 + tid];
    __syncthreads();

    // 2 adjacent channels per thread per cc: c0 = cc*512 + 2*tid
    float accB[2][2][8], accL[2][2][8];
#pragma unroll
    for (int cc = 0; cc < 2; cc++)
#pragma unroll
      for (int q = 0; q < 2; q++)
#pragma unroll
        for (int ll = 0; ll < 8; ll++) { accB[cc][q][ll] = 0.f; accL[cc][q][ll] = 0.f; }

#pragma unroll 8
    for (int h = 0; h < 32; h++) {
      float2 wb[2], wl[2];
#pragma unroll
      for (int cc = 0; cc < 2; cc++) {
        int c0 = cc * 512 + 2 * tid;
        wb[cc] = *(const float2*)(Wb + h * 1024 + c0);
        wl[cc] = *(const float2*)(Wl + h * 1024 + c0);
      }
#pragma unroll
      for (int ll = 0; ll < 8; ll++) {
        float xv = xs[ll][h];
#pragma unroll
        for (int cc = 0; cc < 2; cc++) {
          accB[cc][0][ll] = fmaf(wb[cc].x, xv, accB[cc][0][ll]);
          accB[cc][1][ll] = fmaf(wb[cc].y, xv, accB[cc][1][ll]);
          accL[cc][0][ll] = fmaf(wl[cc].x, xv, accL[cc][0][ll]);
          accL[cc][1][ll] = fmaf(wl[cc].y, xv, accL[cc][1][ll]);
        }
      }
    }
#pragma unroll
    for (int cc = 0; cc < 2; cc++) {
      int c0 = cc * 512 + 2 * tid;
      float2 bbv = *(const float2*)(bb + c0);
      float2 blv = *(const float2*)(bl + c0);
#pragma unroll
      for (int ll = 0; ll < 8; ll++) {
        int l = l0 + ll;
        __hip_bfloat162 hb, hl;
        hb.x = __float2bfloat16(accB[cc][0][ll] + bbv.x);
        hb.y = __float2bfloat16(accB[cc][1][ll] + bbv.y);
        hl.x = __float2bfloat16(silu_f(accL[cc][0][ll] + blv.x));
        hl.y = __float2bfloat16(silu_f(accL[cc][1][ll] + blv.y));
        *(__hip_bfloat162*)(Bp + (size_t)(l + 1) * 1024 + c0) = hb;
        *(__hip_bfloat162*)(Lam + (size_t)l * 1024 + c0) = hl;
      }
    }
    {
      int ll = tid >> 5, jh = tid & 31;
      float a = 0.f;
#pragma unroll
      for (int h = 0; h < 32; h++) a = fmaf(xs[ll][h], Wg[h * 32 + jh], a);
      a += bg[jh];
      gt[(l0 + ll) * 32 + jh] = silu_f(a);
    }
    if (tid < 8) {
      float a = 0.f;
#pragma unroll
      for (int h = 0; h < 32; h++) a = fmaf(xs[tid][h], Wd[h], a);
      a += bd[0];
      Dp[l0 + tid] = (a > 20.f) ? a : log1pf(__expf(a));
    }
    return;
  }
#pragma unroll
  for (int i = 0; i < 4; i++) {
    int c = i * 256 + tid;
    int h = c >> 5;
    float s = __expf(lst[h]);
    float lr = Lre[c], li = Lim[c];
    float er = __expf(lr * s);
    float A0r = er * cosf(li * s);
    float A0i = er * sinf(li * s);
    float den = lr * lr + li * li;
    float nr = A0r - 1.0f, ni = A0i;
    consts[c] = A0r;
    consts[1024 + c] = A0i;
    consts[2048 + c] = cosf(A0i);
    consts[3072 + c] = sinf(A0i);
    consts[4096 + c] = (nr * lr + ni * li) / den;
    consts[5120 + c] = (ni * lr - nr * li) / den;
  }
}

// ================= conv-as-GEMM + T2 XOR swizzle =================
// LDS layout: linear [row][8 slots of 16B]; data at (row, s) = global (row, s^(row&7)).
// Writes: gl_lds16 linear dest, pre-swizzled global source slot.
// Reads: slot s = kslot ^ (row&7)  -> bank-conflict-free (2-way max).
#define BM 128
#define BN 64
__global__ __launch_bounds__(256) void k_conv_gemm(const __hip_bfloat16* __restrict__ A,
                                                   const __hip_bfloat16* __restrict__ BT,
                                                   const float* __restrict__ cb,
                                                   __hip_bfloat16* __restrict__ Bact) {
  __shared__ __align__(16) __hip_bfloat16 As[BM * 64];
  __shared__ __align__(16) __hip_bfloat16 Bs[BN * 64];
  int tid = threadIdx.x;
  int bid = blockIdx.x;
  int swz = (bid & 7) * 64 + (bid >> 3);  // 512 % 8 == 0 -> bijective
  int row0 = (swz >> 4) * BM;
  int col0 = (swz & 15) * BN;
  int lane = tid & 63, wid = tid >> 6;
  int wr = wid >> 1, wc = wid & 1;
  int rA = lane & 15, kg = lane >> 4;
  unsigned wbase = tid & ~63u;

  f32x4 acc[4][2];
#pragma unroll
  for (int m = 0; m < 4; m++)
#pragma unroll
    for (int n = 0; n < 2; n++) acc[m][n] = (f32x4){0.f, 0.f, 0.f, 0.f};

  for (int ks = 0; ks < 64; ks++) {
    int k0 = ks * 64;
#pragma unroll
    for (int i = 0; i < 4; i++) {
      int chunk = i * 256 + tid;
      int m = chunk >> 3, slot = chunk & 7;
      int sl = slot ^ (m & 7);
      gl_lds16(A + (size_t)(row0 + m) * 1024 + k0 + sl * 8, (void*)(As + (size_t)(i * 256 + wbase) * 8));
    }
#pragma unroll
    for (int i = 0; i < 2; i++) {
      int chunk = i * 256 + tid;
      int n = chunk >> 3, slot = chunk & 7;
      int sl = slot ^ (n & 7);
      gl_lds16(BT + (size_t)(col0 + n) * 4096 + k0 + sl * 8, (void*)(Bs + (size_t)(i * 256 + wbase) * 8));
    }
    __syncthreads();

    bf16x8 af[4][2], bfg[2][2];
#pragma unroll
    for (int m = 0; m < 4; m++)
#pragma unroll
      for (int kk = 0; kk < 2; kk++) {
        int row = wr * 64 + m * 16 + rA;
        int s = (kk * 4 + kg) ^ (row & 7);
        af[m][kk] = *(const bf16x8*)(As + row * 64 + s * 8);
      }
#pragma unroll
    for (int n = 0; n < 2; n++)
#pragma unroll
      for (int kk = 0; kk < 2; kk++) {
        int row = wc * 32 + n * 16 + rA;
        int s = (kk * 4 + kg) ^ (row & 7);
        bfg[n][kk] = *(const bf16x8*)(Bs + row * 64 + s * 8);
      }
#pragma unroll
    for (int m = 0; m < 4; m++)
#pragma unroll
      for (int n = 0; n < 2; n++)
#pragma unroll
        for (int kk = 0; kk < 2; kk++)
          acc[m][n] = __builtin_amdgcn_mfma_f32_16x16x32_bf16(af[m][kk], bfg[n][kk], acc[m][n], 0, 0, 0);
    __syncthreads();
  }
#pragma unroll
  for (int m = 0; m < 4; m++)
#pragma unroll
    for (int n = 0; n < 2; n++) {
      int col = col0 + wc * 32 + n * 16 + (lane & 15);
      float cbv = cb[col];
#pragma unroll
      for (int r = 0; r < 4; r++) {
        int row = row0 + wr * 64 + m * 16 + (lane >> 4) * 4 + r;
        Bact[(size_t)row * 1024 + col] = __float2bfloat16(silu_f(acc[m][n][r] + cbv));
      }
    }
}

// ================= scan pass A: 2 channels/thread aggregates =================
__global__ __launch_bounds__(256) void k_scanA(const float* __restrict__ consts,
                                               const __hip_bfloat16* __restrict__ Lam,
                                               const __hip_bfloat16* __restrict__ Bact,
                                               const float* __restrict__ Bin,
                                               float4* __restrict__ Agg) {
  int tid = threadIdx.x;
  int chunk = blockIdx.x >> 1;
  int c0 = (blockIdx.x & 1) * 512 + tid * 2;
  int j0 = c0 & 31;
  float2 A0r = *(const float2*)(consts + c0);
  float2 cz = *(const float2*)(consts + 2048 + c0);
  float2 sz = *(const float2*)(consts + 3072 + c0);
  float2 Bcr = *(const float2*)(consts + 4096 + c0);
  float2 Bci = *(const float2*)(consts + 5120 + c0);
  float ar0 = 1.f, ai0 = 0.f, br0 = 0.f, bi0 = 0.f;
  float ar1 = 1.f, ai1 = 0.f, br1 = 0.f, bi1 = 0.f;
  int l = chunk * CLEN;
#pragma unroll
  for (int it = 0; it < CLEN; it++, l++) {
    unsigned lv = *(const unsigned*)(Lam + (size_t)l * 1024 + c0);
    unsigned bv = *(const unsigned*)(Bact + (size_t)l * 1024 + c0);
    float4 bt = *(const float4*)(Bin + (size_t)l * 64 + j0 * 2);
    float Ar, Ai, Bur, Bui;
    scan_elem(A0r.x, cz.x, sz.x, Bcr.x, Bci.x, bf_lo(lv), bf_lo(bv), bt.x, bt.y, Ar, Ai, Bur, Bui);
    { float nbr = Ar * br0 - Ai * bi0 + Bur, nbi = Ar * bi0 + Ai * br0 + Bui;
      br0 = nbr; bi0 = nbi;
      float nar = Ar * ar0 - Ai * ai0, nai = Ar * ai0 + Ai * ar0;
      ar0 = nar; ai0 = nai; }
    scan_elem(A0r.y, cz.y, sz.y, Bcr.y, Bci.y, bf_hi(lv), bf_hi(bv), bt.z, bt.w, Ar, Ai, Bur, Bui);
    { float nbr = Ar * br1 - Ai * bi1 + Bur, nbi = Ar * bi1 + Ai * br1 + Bui;
      br1 = nbr; bi1 = nbi;
      float nar = Ar * ar1 - Ai * ai1, nai = Ar * ai1 + Ai * ar1;
      ar1 = nar; ai1 = nai; }
  }
  Agg[(size_t)chunk * 1024 + c0] = make_float4(ar0, ai0, br0, bi0);
  Agg[(size_t)chunk * 1024 + c0 + 1] = make_float4(ar1, ai1, br1, bi1);
}

// ================= scan pass B: exclusive carries =================
__global__ __launch_bounds__(256) void k_scanB(const float4* __restrict__ Agg,
                                               float2* __restrict__ Carry) {
  int tid = threadIdx.x;
  int lane = tid & 63;
  int ch = blockIdx.x * 4 + (tid >> 6);
  float pr[8], pi_[8], qr[8], qi[8];
  float mAr = 1.f, mAi = 0.f, mBr = 0.f, mBi = 0.f;
#pragma unroll
  for (int u = 0; u < 8; u++) {
    pr[u] = mAr; pi_[u] = mAi; qr[u] = mBr; qi[u] = mBi;
    float4 g = Agg[(size_t)(lane * 8 + u) * 1024 + ch];
    float nAr = g.x * mAr - g.y * mAi;
    float nAi = g.x * mAi + g.y * mAr;
    float nBr = g.x * mBr - g.y * mBi + g.z;
    float nBi = g.x * mBi + g.y * mBr + g.w;
    mAr = nAr; mAi = nAi; mBr = nBr; mBi = nBi;
  }
  float SAr = mAr, SAi = mAi, SBr = mBr, SBi = mBi;
#pragma unroll
  for (int d = 1; d < 64; d <<= 1) {
    float tAr = __shfl_up(SAr, (unsigned)d, 64);
    float tAi = __shfl_up(SAi, (unsigned)d, 64);
    float tBr = __shfl_up(SBr, (unsigned)d, 64);
    float tBi = __shfl_up(SBi, (unsigned)d, 64);
    if (lane >= d) {
      float nAr = SAr * tAr - SAi * tAi;
      float nAi = SAr * tAi + SAi * tAr;
      float nBr = SAr * tBr - SAi * tBi + SBr;
      float nBi = SAr * tBi + SAi * tBr + SBi;
      SAr = nAr; SAi = nAi; SBr = nBr; SBi = nBi;
    }
  }
  float EBr = __shfl_up(SBr, 1u, 64);
  float EBi = __shfl_up(SBi, 1u, 64);
  if (lane == 0) { EBr = 0.f; EBi = 0.f; }
#pragma unroll
  for (int u = 0; u < 8; u++) {
    float sr = pr[u] * EBr - pi_[u] * EBi + qr[u];
    float si = pr[u] * EBi + pi_[u] * EBr + qi[u];
    Carry[(size_t)(lane * 8 + u) * 1024 + ch] = make_float2(sr, si);
  }
}

// ================= scan pass C: recompute + ys + gate + out GEMM =================
__global__ __launch_bounds__(256) void k_scanC(const float* __restrict__ consts,
                                               const __hip_bfloat16* __restrict__ Lam,
                                               const __hip_bfloat16* __restrict__ Bact,
                                               const float* __restrict__ Bin,
                                               const float* __restrict__ Cin,
                                               const float2* __restrict__ Carry,
                                               const float* __restrict__ x,
                                               const float* __restrict__ gt,
                                               const float* __restrict__ Dp,
                                               const float* __restrict__ Wo,
                                               const float* __restrict__ bo,
                                               float* __restrict__ out) {
  __shared__ float part[4][CLEN][32];
  __shared__ float Wo_s[1024];
  __shared__ float ht_s[CLEN][32];
  int tid = threadIdx.x;
  int chunk = blockIdx.x;
  int l0 = chunk * CLEN;
  int wave = tid >> 6, lane = tid & 63;
#pragma unroll
  for (int i = 0; i < 4; i++) Wo_s[i * 256 + tid] = Wo[i * 256 + tid];

  float ypa[CLEN], ypb[CLEN];
#pragma unroll
  for (int it = 0; it < CLEN; it++) { ypa[it] = 0.f; ypb[it] = 0.f; }

#pragma unroll
  for (int g = 0; g < 2; g++) {
    int c0 = g * 512 + 2 * tid;
    int j0 = c0 & 31, p = c0 >> 5;
    float2 A0r = *(const float2*)(consts + c0);
    float2 cz = *(const float2*)(consts + 2048 + c0);
    float2 sz = *(const float2*)(consts + 3072 + c0);
    float2 Bcr = *(const float2*)(consts + 4096 + c0);
    float2 Bci = *(const float2*)(consts + 5120 + c0);
    float4 sld = *(const float4*)((const float*)Carry + ((size_t)chunk * 1024 + c0) * 2);
    float xr0 = sld.x, xi0 = sld.y, xr1 = sld.z, xi1 = sld.w;
#pragma unroll
    for (int it = 0; it < CLEN; it++) {
      int l = l0 + it;
      unsigned lv = *(const unsigned*)(Lam + (size_t)l * 1024 + c0);
      unsigned bv = *(const unsigned*)(Bact + (size_t)l * 1024 + c0);
      float4 bt = *(const float4*)(Bin + (size_t)l * 64 + j0 * 2);
      float2 cv = *(const float2*)(Cin + (size_t)l * 64 + p * 2);
      float Ar, Ai, Bur, Bui;
      scan_elem(A0r.x, cz.x, sz.x, Bcr.x, Bci.x, bf_lo(lv), bf_lo(bv), bt.x, bt.y, Ar, Ai, Bur, Bui);
      { float nxr = Ar * xr0 - Ai * xi0 + Bur, nxi = Ar * xi0 + Ai * xr0 + Bui;
        xr0 = nxr; xi0 = nxi; }
      ypa[it] = fmaf(cv.x, xr0, ypa[it]);
      ypa[it] = fmaf(-cv.y, xi0, ypa[it]);
      scan_elem(A0r.y, cz.y, sz.y, Bcr.y, Bci.y, bf_hi(lv), bf_hi(bv), bt.z, bt.w, Ar, Ai, Bur, Bui);
      { float nxr = Ar * xr1 - Ai * xi1 + Bur, nxi = Ar * xi1 + Ai * xr1 + Bui;
        xr1 = nxr; xi1 = nxi; }
      ypb[it] = fmaf(cv.x, xr1, ypb[it]);
      ypb[it] = fmaf(-cv.y, xi1, ypb[it]);
    }
  }
  // reduce over p: lanes l, l^16, l^32, l^48 share (j0, j0+1)
#pragma unroll
  for (int it = 0; it < CLEN; it++) {
    ypa[it] += __shfl_xor(ypa[it], 16, 64);
    ypa[it] += __shfl_xor(ypa[it], 32, 64);
    ypb[it] += __shfl_xor(ypb[it], 16, 64);
    ypb[it] += __shfl_xor(ypb[it], 32, 64);
  }
  if (lane < 16) {
#pragma unroll
    for (int it = 0; it < CLEN; it++) {
      part[wave][it][2 * lane] = ypa[it];
      part[wave][it][2 * lane + 1] = ypb[it];
    }
  }
  __syncthreads();
  int ll = tid >> 5, j = tid & 31;
  float ys = part[0][ll][j] + part[1][ll][j] + part[2][ll][j] + part[3][ll][j];
  int l = l0 + ll;
  float xv = x[l * 32 + j];
  float g = gt[l * 32 + j];
  float d = Dp[l];
  float ht = (1.0f - g) * (ys + d * xv) + g * xv;
  ht_s[ll][j] = ht;
  __syncthreads();
  float accv = bo[j];
#pragma unroll
  for (int jj = 0; jj < 32; jj++) accv = fmaf(ht_s[ll][jj], Wo_s[jj * 32 + j], accv);
  out[l * 32 + j] = accv;
}

extern "C" void kernel_launch(void* const* d_in, const int* in_sizes, int n_in,
                              void* d_out, int out_size, void* d_ws, size_t ws_size,
                              hipStream_t stream) {
  const float* x   = (const float*)d_in[0];
  const float* Lre = (const float*)d_in[1];
  const float* Lim = (const float*)d_in[2];
  const float* Bin = (const float*)d_in[3];
  const float* Cin = (const float*)d_in[4];
  const float* lst = (const float*)d_in[5];
  const float* Wb  = (const float*)d_in[6];
  const float* bb  = (const float*)d_in[7];
  const float* Wl  = (const float*)d_in[8];
  const float* bl  = (const float*)d_in[9];
  const float* cw  = (const float*)d_in[10];
  const float* cb  = (const float*)d_in[11];
  const float* Wg  = (const float*)d_in[12];
  const float* bg  = (const float*)d_in[13];
  const float* Wd  = (const float*)d_in[14];
  const float* bd  = (const float*)d_in[15];
  const float* Wo  = (const float*)d_in[16];
  const float* bo  = (const float*)d_in[17];
  float* out = (float*)d_out;

  char* ws = (char*)d_ws;
  size_t off = 0;
  auto alloc = [&](size_t bytes) {
    char* p = ws + off;
    off = (off + bytes + 255) & ~(size_t)255;
    return p;
  };
  float* consts          = (float*)alloc(6 * 1024 * 4);
  __hip_bfloat16* Bp     = (__hip_bfloat16*)alloc((size_t)(LSEQ + 3) * 1024 * 2);
  __hip_bfloat16* WT     = (__hip_bfloat16*)alloc((size_t)1024 * 4096 * 2);
  __hip_bfloat16* Lam    = (__hip_bfloat16*)alloc((size_t)LSEQ * 1024 * 2);
  __hip_bfloat16* Bact   = (__hip_bfloat16*)alloc((size_t)LSEQ * 1024 * 2);
  float* gt              = (float*)alloc((size_t)LSEQ * 32 * 4);
  float* Dp              = (float*)alloc((size_t)LSEQ * 4);
  float4* Agg            = (float4*)alloc((size_t)NCHUNK * 1024 * 16);
  float2* Carry          = (float2*)alloc((size_t)NCHUNK * 1024 * 8);

  k_prep<<<4609, 256, 0, stream>>>(x, Wb, bb, Wl, bl, Wg, bg, Wd, bd, cw,
                                   Lre, Lim, lst, Bp, Lam, gt, Dp, WT, consts);
  k_conv_gemm<<<512, 256, 0, stream>>>(Bp, WT, cb, Bact);
  k_scanA<<<2 * NCHUNK, 256, 0, stream>>>(consts, Lam, Bact, Bin, Agg);
  k_scanB<<<256, 256, 0, stream>>>(Agg, Carry);
  k_scanC<<<NCHUNK, 256, 0, stream>>>(consts, Lam, Bact, Bin, Cin, Carry, x, gt, Dp, Wo, bo, out);
}

// Round 15
// 192.881 us; speedup vs baseline: 1.2616x; 1.0175x over previous
//
#include <hip/hip_runtime.h>
#include <hip/hip_bf16.h>

#define LSEQ 4096
#define CLEN 8
#define NCHUNK 512

typedef __attribute__((ext_vector_type(8))) short bf16x8;
typedef __attribute__((ext_vector_type(4))) float f32x4;

__device__ __forceinline__ void gl_lds16(const void* g, void* l) {
  __builtin_amdgcn_global_load_lds(
      (const __attribute__((address_space(1))) unsigned int*)g,
      (__attribute__((address_space(3))) unsigned int*)l, 16, 0, 0);
}

__device__ __forceinline__ float silu_f(float v) { return v / (1.0f + __expf(-v)); }

__device__ __forceinline__ float bf_lo(unsigned v) { return __uint_as_float(v << 16); }
__device__ __forceinline__ float bf_hi(unsigned v) { return __uint_as_float(v & 0xffff0000u); }

// atan(t) for |t| <= ~0.8 (wr = 1 + e*cos(A0i) > 1.4 guaranteed)
__device__ __forceinline__ float atan_small(float t) {
  float t2 = t * t;
  float p = fmaf(t2, fmaf(t2, fmaf(t2, fmaf(t2, 0.11111111f, -0.14285714f), 0.2f),
                          -0.33333333f), 1.0f);
  return t * p;
}

__device__ __forceinline__ void scan_elem(float A0r, float cz, float sz, float Bcr, float Bci,
                                          float La, float Ba, float btr, float bti,
                                          float& Ar, float& Ai, float& Bur, float& Bui) {
  float e = __expf(A0r + La);
  float wr = fmaf(e, cz, 1.0f), wi = e * sz;
  Ar = 0.5f * __logf(fmaf(wr, wr, wi * wi));
  Ai = atan_small(wi * __builtin_amdgcn_rcpf(wr));
  float pr = Bcr * btr - Bci * bti;
  float pi = Bcr * bti + Bci * btr;
  Bur = pr * Ba;
  Bui = pi * Ba;
}

// ================= fused prep kernel =================
// blocks [0,4096): transpose conv_w -> WT bf16; [4096,4608): proj; 4608: consts
__global__ __launch_bounds__(256) void k_prep(
    const float* __restrict__ x, const float* __restrict__ Wb, const float* __restrict__ bb,
    const float* __restrict__ Wl, const float* __restrict__ bl,
    const float* __restrict__ Wg, const float* __restrict__ bg,
    const float* __restrict__ Wd, const float* __restrict__ bd,
    const float* __restrict__ cw,
    const float* __restrict__ Lre, const float* __restrict__ Lim, const float* __restrict__ lst,
    __hip_bfloat16* __restrict__ Bp, __hip_bfloat16* __restrict__ Lam,
    float* __restrict__ gt, float* __restrict__ Dp,
    __hip_bfloat16* __restrict__ WT, float* __restrict__ consts) {
  int b = blockIdx.x;
  int tid = threadIdx.x;
  if (b < 4096) {
    __shared__ float t[32][33];
    int k0 = (b & 127) * 32;
    int n0 = (b >> 7) * 32;
    int r = tid >> 5, cidx = tid & 31;
#pragma unroll
    for (int i = 0; i < 4; i++)
      t[r + i * 8][cidx] = cw[(size_t)(k0 + r + i * 8) * 1024 + n0 + cidx];
    __syncthreads();
#pragma unroll
    for (int i = 0; i < 4; i++) {
      int a = r + i * 8;
      WT[(size_t)(n0 + a) * 4096 + k0 + cidx] = __float2bfloat16(t[cidx][a]);
    }
    return;
  }
  if (b < 4608) {
    int pb = b - 4096;
    if (pb == 0) {
#pragma unroll
      for (int i = 0; i < 4; i++) {
        int c = i * 256 + tid;
        Bp[c] = __float2bfloat16(0.f);
        Bp[(size_t)(LSEQ + 1) * 1024 + c] = __float2bfloat16(0.f);
        Bp[(size_t)(LSEQ + 2) * 1024 + c] = __float2bfloat16(0.f);
      }
    }
    __shared__ float xs[8][32];
    int l0 = pb * 8;
    xs[tid >> 5][tid & 31] = x[l0 * 32 + tid];
    __syncthreads();

    float accB[2][2][8], accL[2][2][8];
#pragma unroll
    for (int cc = 0; cc < 2; cc++)
#pragma unroll
      for (int q = 0; q < 2; q++)
#pragma unroll
        for (int ll = 0; ll < 8; ll++) { accB[cc][q][ll] = 0.f; accL[cc][q][ll] = 0.f; }

#pragma unroll 8
    for (int h = 0; h < 32; h++) {
      float2 wb[2], wl[2];
#pragma unroll
      for (int cc = 0; cc < 2; cc++) {
        int c0 = cc * 512 + 2 * tid;
        wb[cc] = *(const float2*)(Wb + h * 1024 + c0);
        wl[cc] = *(const float2*)(Wl + h * 1024 + c0);
      }
#pragma unroll
      for (int ll = 0; ll < 8; ll++) {
        float xv = xs[ll][h];
#pragma unroll
        for (int cc = 0; cc < 2; cc++) {
          accB[cc][0][ll] = fmaf(wb[cc].x, xv, accB[cc][0][ll]);
          accB[cc][1][ll] = fmaf(wb[cc].y, xv, accB[cc][1][ll]);
          accL[cc][0][ll] = fmaf(wl[cc].x, xv, accL[cc][0][ll]);
          accL[cc][1][ll] = fmaf(wl[cc].y, xv, accL[cc][1][ll]);
        }
      }
    }
#pragma unroll
    for (int cc = 0; cc < 2; cc++) {
      int c0 = cc * 512 + 2 * tid;
      float2 bbv = *(const float2*)(bb + c0);
      float2 blv = *(const float2*)(bl + c0);
#pragma unroll
      for (int ll = 0; ll < 8; ll++) {
        int l = l0 + ll;
        __hip_bfloat162 hb, hl;
        hb.x = __float2bfloat16(accB[cc][0][ll] + bbv.x);
        hb.y = __float2bfloat16(accB[cc][1][ll] + bbv.y);
        hl.x = __float2bfloat16(silu_f(accL[cc][0][ll] + blv.x));
        hl.y = __float2bfloat16(silu_f(accL[cc][1][ll] + blv.y));
        *(__hip_bfloat162*)(Bp + (size_t)(l + 1) * 1024 + c0) = hb;
        *(__hip_bfloat162*)(Lam + (size_t)l * 1024 + c0) = hl;
      }
    }
    {
      int ll = tid >> 5, jh = tid & 31;
      float a = 0.f;
#pragma unroll
      for (int h = 0; h < 32; h++) a = fmaf(xs[ll][h], Wg[h * 32 + jh], a);
      a += bg[jh];
      gt[(l0 + ll) * 32 + jh] = silu_f(a);
    }
    if (tid < 8) {
      float a = 0.f;
#pragma unroll
      for (int h = 0; h < 32; h++) a = fmaf(xs[tid][h], Wd[h], a);
      a += bd[0];
      Dp[l0 + tid] = (a > 20.f) ? a : log1pf(__expf(a));
    }
    return;
  }
#pragma unroll
  for (int i = 0; i < 4; i++) {
    int c = i * 256 + tid;
    int h = c >> 5;
    float s = __expf(lst[h]);
    float lr = Lre[c], li = Lim[c];
    float er = __expf(lr * s);
    float A0r = er * cosf(li * s);
    float A0i = er * sinf(li * s);
    float den = lr * lr + li * li;
    float nr = A0r - 1.0f, ni = A0i;
    consts[c] = A0r;
    consts[1024 + c] = A0i;
    consts[2048 + c] = cosf(A0i);
    consts[3072 + c] = sinf(A0i);
    consts[4096 + c] = (nr * lr + ni * li) / den;
    consts[5120 + c] = (ni * lr - nr * li) / den;
  }
}

// ================= conv-as-GEMM, BK=128 (32 K-steps), T2 XOR swizzle =================
// LDS: linear [row][16 slots of 16B]; data at (row, s) = global (row, s^(row&7)).
// Writes: gl_lds16 linear dest, pre-swizzled global source slot.
// Reads: slot s = kslot ^ (row&7) -> <=2-way banks.
#define BM 128
#define BN 64
#define BK 128
__global__ __launch_bounds__(256) void k_conv_gemm(const __hip_bfloat16* __restrict__ A,
                                                   const __hip_bfloat16* __restrict__ BT,
                                                   const float* __restrict__ cb,
                                                   __hip_bfloat16* __restrict__ Bact) {
  __shared__ __align__(16) __hip_bfloat16 As[BM * BK];  // 32 KB
  __shared__ __align__(16) __hip_bfloat16 Bs[BN * BK];  // 16 KB
  int tid = threadIdx.x;
  int bid = blockIdx.x;
  int swz = (bid & 7) * 64 + (bid >> 3);  // 512 % 8 == 0 -> bijective
  int row0 = (swz >> 4) * BM;
  int col0 = (swz & 15) * BN;
  int lane = tid & 63, wid = tid >> 6;
  int wr = wid >> 1, wc = wid & 1;
  int rA = lane & 15, kg = lane >> 4;
  unsigned wbase = tid & ~63u;

  f32x4 acc[4][2];
#pragma unroll
  for (int m = 0; m < 4; m++)
#pragma unroll
    for (int n = 0; n < 2; n++) acc[m][n] = (f32x4){0.f, 0.f, 0.f, 0.f};

  for (int ks = 0; ks < 32; ks++) {
    int k0 = ks * BK;
    // A: 128 rows x 16 slots = 2048 chunks, 8 per thread
#pragma unroll
    for (int i = 0; i < 8; i++) {
      int chunk = i * 256 + tid;
      int m = chunk >> 4, slot = chunk & 15;
      int sl = slot ^ (m & 7);
      gl_lds16(A + (size_t)(row0 + m) * 1024 + k0 + sl * 8, (void*)(As + (size_t)(i * 256 + wbase) * 8));
    }
    // B: 64 rows x 16 slots = 1024 chunks, 4 per thread
#pragma unroll
    for (int i = 0; i < 4; i++) {
      int chunk = i * 256 + tid;
      int n = chunk >> 4, slot = chunk & 15;
      int sl = slot ^ (n & 7);
      gl_lds16(BT + (size_t)(col0 + n) * 4096 + k0 + sl * 8, (void*)(Bs + (size_t)(i * 256 + wbase) * 8));
    }
    __syncthreads();

    bf16x8 af[4][4], bfg[2][4];
#pragma unroll
    for (int m = 0; m < 4; m++)
#pragma unroll
      for (int kk = 0; kk < 4; kk++) {
        int row = wr * 64 + m * 16 + rA;
        int s = (kk * 4 + kg) ^ (row & 7);
        af[m][kk] = *(const bf16x8*)(As + row * BK + s * 8);
      }
#pragma unroll
    for (int n = 0; n < 2; n++)
#pragma unroll
      for (int kk = 0; kk < 4; kk++) {
        int row = wc * 32 + n * 16 + rA;
        int s = (kk * 4 + kg) ^ (row & 7);
        bfg[n][kk] = *(const bf16x8*)(Bs + row * BK + s * 8);
      }
#pragma unroll
    for (int m = 0; m < 4; m++)
#pragma unroll
      for (int n = 0; n < 2; n++)
#pragma unroll
        for (int kk = 0; kk < 4; kk++)
          acc[m][n] = __builtin_amdgcn_mfma_f32_16x16x32_bf16(af[m][kk], bfg[n][kk], acc[m][n], 0, 0, 0);
    __syncthreads();
  }
#pragma unroll
  for (int m = 0; m < 4; m++)
#pragma unroll
    for (int n = 0; n < 2; n++) {
      int col = col0 + wc * 32 + n * 16 + (lane & 15);
      float cbv = cb[col];
#pragma unroll
      for (int r = 0; r < 4; r++) {
        int row = row0 + wr * 64 + m * 16 + (lane >> 4) * 4 + r;
        Bact[(size_t)row * 1024 + col] = __float2bfloat16(silu_f(acc[m][n][r] + cbv));
      }
    }
}

// ================= scan pass A: 2 channels/thread aggregates =================
__global__ __launch_bounds__(256) void k_scanA(const float* __restrict__ consts,
                                               const __hip_bfloat16* __restrict__ Lam,
                                               const __hip_bfloat16* __restrict__ Bact,
                                               const float* __restrict__ Bin,
                                               float4* __restrict__ Agg) {
  int tid = threadIdx.x;
  int chunk = blockIdx.x >> 1;
  int c0 = (blockIdx.x & 1) * 512 + tid * 2;
  int j0 = c0 & 31;
  float2 A0r = *(const float2*)(consts + c0);
  float2 cz = *(const float2*)(consts + 2048 + c0);
  float2 sz = *(const float2*)(consts + 3072 + c0);
  float2 Bcr = *(const float2*)(consts + 4096 + c0);
  float2 Bci = *(const float2*)(consts + 5120 + c0);
  float ar0 = 1.f, ai0 = 0.f, br0 = 0.f, bi0 = 0.f;
  float ar1 = 1.f, ai1 = 0.f, br1 = 0.f, bi1 = 0.f;
  int l = chunk * CLEN;
#pragma unroll
  for (int it = 0; it < CLEN; it++, l++) {
    unsigned lv = *(const unsigned*)(Lam + (size_t)l * 1024 + c0);
    unsigned bv = *(const unsigned*)(Bact + (size_t)l * 1024 + c0);
    float4 bt = *(const float4*)(Bin + (size_t)l * 64 + j0 * 2);
    float Ar, Ai, Bur, Bui;
    scan_elem(A0r.x, cz.x, sz.x, Bcr.x, Bci.x, bf_lo(lv), bf_lo(bv), bt.x, bt.y, Ar, Ai, Bur, Bui);
    { float nbr = Ar * br0 - Ai * bi0 + Bur, nbi = Ar * bi0 + Ai * br0 + Bui;
      br0 = nbr; bi0 = nbi;
      float nar = Ar * ar0 - Ai * ai0, nai = Ar * ai0 + Ai * ar0;
      ar0 = nar; ai0 = nai; }
    scan_elem(A0r.y, cz.y, sz.y, Bcr.y, Bci.y, bf_hi(lv), bf_hi(bv), bt.z, bt.w, Ar, Ai, Bur, Bui);
    { float nbr = Ar * br1 - Ai * bi1 + Bur, nbi = Ar * bi1 + Ai * br1 + Bui;
      br1 = nbr; bi1 = nbi;
      float nar = Ar * ar1 - Ai * ai1, nai = Ar * ai1 + Ai * ar1;
      ar1 = nar; ai1 = nai; }
  }
  Agg[(size_t)chunk * 1024 + c0] = make_float4(ar0, ai0, br0, bi0);
  Agg[(size_t)chunk * 1024 + c0 + 1] = make_float4(ar1, ai1, br1, bi1);
}

// ================= scan pass B: exclusive carries =================
__global__ __launch_bounds__(256) void k_scanB(const float4* __restrict__ Agg,
                                               float2* __restrict__ Carry) {
  int tid = threadIdx.x;
  int lane = tid & 63;
  int ch = blockIdx.x * 4 + (tid >> 6);
  float pr[8], pi_[8], qr[8], qi[8];
  float mAr = 1.f, mAi = 0.f, mBr = 0.f, mBi = 0.f;
#pragma unroll
  for (int u = 0; u < 8; u++) {
    pr[u] = mAr; pi_[u] = mAi; qr[u] = mBr; qi[u] = mBi;
    float4 g = Agg[(size_t)(lane * 8 + u) * 1024 + ch];
    float nAr = g.x * mAr - g.y * mAi;
    float nAi = g.x * mAi + g.y * mAr;
    float nBr = g.x * mBr - g.y * mBi + g.z;
    float nBi = g.x * mBi + g.y * mBr + g.w;
    mAr = nAr; mAi = nAi; mBr = nBr; mBi = nBi;
  }
  float SAr = mAr, SAi = mAi, SBr = mBr, SBi = mBi;
#pragma unroll
  for (int d = 1; d < 64; d <<= 1) {
    float tAr = __shfl_up(SAr, (unsigned)d, 64);
    float tAi = __shfl_up(SAi, (unsigned)d, 64);
    float tBr = __shfl_up(SBr, (unsigned)d, 64);
    float tBi = __shfl_up(SBi, (unsigned)d, 64);
    if (lane >= d) {
      float nAr = SAr * tAr - SAi * tAi;
      float nAi = SAr * tAi + SAi * tAr;
      float nBr = SAr * tBr - SAi * tBi + SBr;
      float nBi = SAr * tBi + SAi * tBr + SBi;
      SAr = nAr; SAi = nAi; SBr = nBr; SBi = nBi;
    }
  }
  float EBr = __shfl_up(SBr, 1u, 64);
  float EBi = __shfl_up(SBi, 1u, 64);
  if (lane == 0) { EBr = 0.f; EBi = 0.f; }
#pragma unroll
  for (int u = 0; u < 8; u++) {
    float sr = pr[u] * EBr - pi_[u] * EBi + qr[u];
    float si = pr[u] * EBi + pi_[u] * EBr + qi[u];
    Carry[(size_t)(lane * 8 + u) * 1024 + ch] = make_float2(sr, si);
  }
}

// ================= scan pass C: recompute + ys + gate + out GEMM =================
__global__ __launch_bounds__(256) void k_scanC(const float* __restrict__ consts,
                                               const __hip_bfloat16* __restrict__ Lam,
                                               const __hip_bfloat16* __restrict__ Bact,
                                               const float* __restrict__ Bin,
                                               const float* __restrict__ Cin,
                                               const float2* __restrict__ Carry,
                                               const float* __restrict__ x,
                                               const float* __restrict__ gt,
                                               const float* __restrict__ Dp,
                                               const float* __restrict__ Wo,
                                               const float* __restrict__ bo,
                                               float* __restrict__ out) {
  __shared__ float part[4][CLEN][32];
  __shared__ float Wo_s[1024];
  __shared__ float ht_s[CLEN][32];
  int tid = threadIdx.x;
  int chunk = blockIdx.x;
  int l0 = chunk * CLEN;
  int wave = tid >> 6, lane = tid & 63;
#pragma unroll
  for (int i = 0; i < 4; i++) Wo_s[i * 256 + tid] = Wo[i * 256 + tid];

  float ypa[CLEN], ypb[CLEN];
#pragma unroll
  for (int it = 0; it < CLEN; it++) { ypa[it] = 0.f; ypb[it] = 0.f; }

#pragma unroll
  for (int g = 0; g < 2; g++) {
    int c0 = g * 512 + 2 * tid;
    int j0 = c0 & 31, p = c0 >> 5;
    float2 A0r = *(const float2*)(consts + c0);
    float2 cz = *(const float2*)(consts + 2048 + c0);
    float2 sz = *(const float2*)(consts + 3072 + c0);
    float2 Bcr = *(const float2*)(consts + 4096 + c0);
    float2 Bci = *(const float2*)(consts + 5120 + c0);
    float4 sld = *(const float4*)((const float*)Carry + ((size_t)chunk * 1024 + c0) * 2);
    float xr0 = sld.x, xi0 = sld.y, xr1 = sld.z, xi1 = sld.w;
#pragma unroll
    for (int it = 0; it < CLEN; it++) {
      int l = l0 + it;
      unsigned lv = *(const unsigned*)(Lam + (size_t)l * 1024 + c0);
      unsigned bv = *(const unsigned*)(Bact + (size_t)l * 1024 + c0);
      float4 bt = *(const float4*)(Bin + (size_t)l * 64 + j0 * 2);
      float2 cv = *(const float2*)(Cin + (size_t)l * 64 + p * 2);
      float Ar, Ai, Bur, Bui;
      scan_elem(A0r.x, cz.x, sz.x, Bcr.x, Bci.x, bf_lo(lv), bf_lo(bv), bt.x, bt.y, Ar, Ai, Bur, Bui);
      { float nxr = Ar * xr0 - Ai * xi0 + Bur, nxi = Ar * xi0 + Ai * xr0 + Bui;
        xr0 = nxr; xi0 = nxi; }
      ypa[it] = fmaf(cv.x, xr0, ypa[it]);
      ypa[it] = fmaf(-cv.y, xi0, ypa[it]);
      scan_elem(A0r.y, cz.y, sz.y, Bcr.y, Bci.y, bf_hi(lv), bf_hi(bv), bt.z, bt.w, Ar, Ai, Bur, Bui);
      { float nxr = Ar * xr1 - Ai * xi1 + Bur, nxi = Ar * xi1 + Ai * xr1 + Bui;
        xr1 = nxr; xi1 = nxi; }
      ypb[it] = fmaf(cv.x, xr1, ypb[it]);
      ypb[it] = fmaf(-cv.y, xi1, ypb[it]);
    }
  }
  // reduce over p: lanes l, l^16, l^32, l^48 share (j0, j0+1)
#pragma unroll
  for (int it = 0; it < CLEN; it++) {
    ypa[it] += __shfl_xor(ypa[it], 16, 64);
    ypa[it] += __shfl_xor(ypa[it], 32, 64);
    ypb[it] += __shfl_xor(ypb[it], 16, 64);
    ypb[it] += __shfl_xor(ypb[it], 32, 64);
  }
  if (lane < 16) {
#pragma unroll
    for (int it = 0; it < CLEN; it++) {
      part[wave][it][2 * lane] = ypa[it];
      part[wave][it][2 * lane + 1] = ypb[it];
    }
  }
  __syncthreads();
  int ll = tid >> 5, j = tid & 31;
  float ys = part[0][ll][j] + part[1][ll][j] + part[2][ll][j] + part[3][ll][j];
  int l = l0 + ll;
  float xv = x[l * 32 + j];
  float g = gt[l * 32 + j];
  float d = Dp[l];
  float ht = (1.0f - g) * (ys + d * xv) + g * xv;
  ht_s[ll][j] = ht;
  __syncthreads();
  float accv = bo[j];
#pragma unroll
  for (int jj = 0; jj < 32; jj++) accv = fmaf(ht_s[ll][jj], Wo_s[jj * 32 + j], accv);
  out[l * 32 + j] = accv;
}

extern "C" void kernel_launch(void* const* d_in, const int* in_sizes, int n_in,
                              void* d_out, int out_size, void* d_ws, size_t ws_size,
                              hipStream_t stream) {
  const float* x   = (const float*)d_in[0];
  const float* Lre = (const float*)d_in[1];
  const float* Lim = (const float*)d_in[2];
  const float* Bin = (const float*)d_in[3];
  const float* Cin = (const float*)d_in[4];
  const float* lst = (const float*)d_in[5];
  const float* Wb  = (const float*)d_in[6];
  const float* bb  = (const float*)d_in[7];
  const float* Wl  = (const float*)d_in[8];
  const float* bl  = (const float*)d_in[9];
  const float* cw  = (const float*)d_in[10];
  const float* cb  = (const float*)d_in[11];
  const float* Wg  = (const float*)d_in[12];
  const float* bg  = (const float*)d_in[13];
  const float* Wd  = (const float*)d_in[14];
  const float* bd  = (const float*)d_in[15];
  const float* Wo  = (const float*)d_in[16];
  const float* bo  = (const float*)d_in[17];
  float* out = (float*)d_out;

  char* ws = (char*)d_ws;
  size_t off = 0;
  auto alloc = [&](size_t bytes) {
    char* p = ws + off;
    off = (off + bytes + 255) & ~(size_t)255;
    return p;
  };
  float* consts          = (float*)alloc(6 * 1024 * 4);
  __hip_bfloat16* Bp     = (__hip_bfloat16*)alloc((size_t)(LSEQ + 3) * 1024 * 2);
  __hip_bfloat16* WT     = (__hip_bfloat16*)alloc((size_t)1024 * 4096 * 2);
  __hip_bfloat16* Lam    = (__hip_bfloat16*)alloc((size_t)LSEQ * 1024 * 2);
  __hip_bfloat16* Bact   = (__hip_bfloat16*)alloc((size_t)LSEQ * 1024 * 2);
  float* gt              = (float*)alloc((size_t)LSEQ * 32 * 4);
  float* Dp              = (float*)alloc((size_t)LSEQ * 4);
  float4* Agg            = (float4*)alloc((size_t)NCHUNK * 1024 * 16);
  float2* Carry          = (float2*)alloc((size_t)NCHUNK * 1024 * 8);

  k_prep<<<4609, 256, 0, stream>>>(x, Wb, bb, Wl, bl, Wg, bg, Wd, bd, cw,
                                   Lre, Lim, lst, Bp, Lam, gt, Dp, WT, consts);
  k_conv_gemm<<<512, 256, 0, stream>>>(Bp, WT, cb, Bact);
  k_scanA<<<2 * NCHUNK, 256, 0, stream>>>(consts, Lam, Bact, Bin, Agg);
  k_scanB<<<256, 256, 0, stream>>>(Agg, Carry);
  k_scanC<<<NCHUNK, 256, 0, stream>>>(consts, Lam, Bact, Bin, Cin, Carry, x, gt, Dp, Wo, bo, out);
}